// Round 2
// baseline (2677.190 us; speedup 1.0000x reference)
//
#include <hip/hip_runtime.h>
#include <hip/hip_bf16.h>
#include <math.h>

// ---------------- types ----------------
typedef __bf16 bf16;
typedef __bf16 bf16x8 __attribute__((ext_vector_type(8)));
typedef float  f32x4  __attribute__((ext_vector_type(4)));

// ---------------- model constants ----------------
#define NB   32        // batch
#define ED   768       // embed dim
#define NH   12        // heads
#define DHD  64        // head dim
#define FFD  3072
#define TT1  196       // pre-stack tokens
#define TT2  41        // short-stack tokens
#define TPM  208       // padded token dim (row stride for q/k/rk/S/prob)
#define KPM  224       // padded K dim for PV (col stride for prob/vT)
#define MM1  6272      // 196*32  (= 49*128)
#define MM2  1408      // padded 41*32=1312 -> 11*128
#define M2R  1312
#define BHN  384       // 32*12
#define LTOT 10
#define SCL  0.125f    // 1/sqrt(64)

// ---------------- helpers ----------------
__device__ __forceinline__ float block_sum(float v, float* red, int tid) {
#pragma unroll
  for (int o = 32; o; o >>= 1) v += __shfl_xor(v, o);
  if ((tid & 63) == 0) red[tid >> 6] = v;
  __syncthreads();
  float t = red[0] + red[1] + red[2] + red[3];
  __syncthreads();
  return t;
}

// ---------------- fp32 -> bf16 converters ----------------
__global__ void k_cvt(const float* __restrict__ s, bf16* __restrict__ d, long n) {
  for (long i = (long)blockIdx.x * 256 + threadIdx.x; i < n; i += (long)gridDim.x * 256)
    d[i] = (bf16)s[i];
}

__global__ void k_cvt4(const float* __restrict__ a, const float* __restrict__ b,
                       const float* __restrict__ c, const float* __restrict__ d,
                       bf16* __restrict__ oa, bf16* __restrict__ ob,
                       bf16* __restrict__ oc, bf16* __restrict__ od,
                       int na, int nb, int nc, int nd) {
  long tot = (long)na + nb + nc + nd;
  for (long i = (long)blockIdx.x * 256 + threadIdx.x; i < tot; i += (long)gridDim.x * 256) {
    if (i < na) oa[i] = (bf16)a[i];
    else if (i < (long)na + nb) ob[i - na] = (bf16)b[i - na];
    else if (i < (long)na + nb + nc) oc[i - na - nb] = (bf16)c[i - na - nb];
    else od[i - na - nb - nc] = (bf16)d[i - na - nb - nc];
  }
}

// ---------------- sinusoidal pos emb (descending pos), bf16 out ----------------
__global__ void k_posemb(bf16* __restrict__ out, int T) {
  const int t = blockIdx.x, c = threadIdx.x;   // block = 768
  float v = 0.0f;
  if (t < T) {
    const float pos = (float)(T - 1 - t);
    const int ci = (c < 384) ? c : c - 384;
    const float invf = expf(-(float)ci * (9.210340371976184f / 384.0f)); // ln(10000)
    const float a = pos * invf;
    v = (c < 384) ? sinf(a) : cosf(a);
  }
  out[(long)t * ED + c] = (bf16)v;
}

// ---------------- im2col for patch embed: A0[t*32+b][c*256+i*16+j] ----------------
__global__ void k_im2col(const float* __restrict__ x, bf16* __restrict__ A0) {
  const long idx = (long)blockIdx.x * 256 + threadIdx.x;
  if (idx >= (long)MM1 * ED) return;
  const int row = (int)(idx / ED), k = (int)(idx % ED);
  const int t = row >> 5, b = row & 31;
  const int c = k >> 8, rem = k & 255, i = rem >> 4, j = rem & 15;
  const int py = t / 14, px = t % 14;
  A0[idx] = (bf16)x[((long)(b * 3 + c) * 224 + (py * 16 + i)) * 224 + px * 16 + j];
}

// ---------------- GEMM: C[m,n] = sum_k A[m,k]*B[n,k] + bias[n] ----------------
// 128x128 tile, BK=64, 4 waves. EPI: 0=fp32; 1=GELU->bf16; 2=fp32+bf16; 3=bf16.
template <int EPI>
__global__ __launch_bounds__(256) void k_gemm(const bf16* __restrict__ A, const bf16* __restrict__ Bw,
                                              const float* __restrict__ bias,
                                              float* __restrict__ Cf, bf16* __restrict__ Cb,
                                              int M, int N, int K) {
  __shared__ __align__(16) bf16 As[128 * 64];
  __shared__ __align__(16) bf16 Bs[128 * 64];
  const int tid = threadIdx.x;
  const int l = tid & 63, w = tid >> 6;
  const int wr = w >> 1, wc = w & 1;
  const int m0 = blockIdx.y * 128, n0 = blockIdx.x * 128;
  const int srow = tid >> 3;          // 32 rows per staging pass
  const int scol = (tid & 7) * 8;
  f32x4 acc[4][4] = {};
  for (int k0 = 0; k0 < K; k0 += 64) {
    __syncthreads();
#pragma unroll
    for (int ps = 0; ps < 4; ++ps) {
      const int r = ps * 32 + srow;
      *(bf16x8*)&As[r * 64 + scol] = *(const bf16x8*)&A[(long)(m0 + r) * K + k0 + scol];
      *(bf16x8*)&Bs[r * 64 + scol] = *(const bf16x8*)&Bw[(long)(n0 + r) * K + k0 + scol];
    }
    __syncthreads();
#pragma unroll
    for (int kk = 0; kk < 64; kk += 32) {
      bf16x8 af[4], bg[4];
#pragma unroll
      for (int m = 0; m < 4; ++m)
        af[m] = *(const bf16x8*)&As[(wr * 64 + m * 16 + (l & 15)) * 64 + kk + 8 * (l >> 4)];
#pragma unroll
      for (int n = 0; n < 4; ++n)
        bg[n] = *(const bf16x8*)&Bs[(wc * 64 + n * 16 + (l & 15)) * 64 + kk + 8 * (l >> 4)];
#pragma unroll
      for (int m = 0; m < 4; ++m)
#pragma unroll
        for (int n = 0; n < 4; ++n)
          acc[m][n] = __builtin_amdgcn_mfma_f32_16x16x32_bf16(af[m], bg[n], acc[m][n], 0, 0, 0);
    }
  }
#pragma unroll
  for (int m = 0; m < 4; ++m) {
    const int row = m0 + wr * 64 + m * 16 + 4 * (l >> 4);
#pragma unroll
    for (int n = 0; n < 4; ++n) {
      const int col = n0 + wc * 64 + n * 16 + (l & 15);
      const float bv = bias[col];
#pragma unroll
      for (int r = 0; r < 4; ++r) {
        const float v = acc[m][n][r] + bv;
        const long off = (long)(row + r) * N + col;
        if (EPI == 0) {
          Cf[off] = v;
        } else if (EPI == 1) {
          Cb[off] = (bf16)(0.5f * v * (1.0f + erff(v * 0.70710678118654752f)));
        } else if (EPI == 2) {
          Cf[off] = v;
          Cb[off] = (bf16)v;
        } else {
          Cb[off] = (bf16)v;
        }
      }
    }
  }
}

// ---------------- repack qkv heads -> attention layouts ----------------
// qw/qr/kk: [bh][TPM][64] bf16 (rows >= T zeroed). vT: [bh][64][KPM] bf16.
__global__ void k_repack(const bf16* __restrict__ heads, const float* __restrict__ rwb,
                         const float* __restrict__ rrb,
                         bf16* __restrict__ qw, bf16* __restrict__ qr,
                         bf16* __restrict__ kkb, bf16* __restrict__ vT, int T) {
  const int i = blockIdx.x, bh = blockIdx.y, d = threadIdx.x;  // block = 64
  const int b = bh / NH, n = bh % NH;
  const long qoff = (long)bh * TPM * 64 + (long)i * 64 + d;
  const long voff = (long)bh * 64 * KPM + (long)d * KPM + i;
  if (i < T) {
    const long src = ((long)(i * NB + b)) * (3 * ED) + n * 64 + d;
    const float q = (float)heads[src];
    qw[qoff] = (bf16)(q + rwb[n * 64 + d]);
    qr[qoff] = (bf16)(q + rrb[n * 64 + d]);
    kkb[qoff] = heads[src + ED];
    vT[voff] = heads[src + 2 * ED];
  } else {
    qw[qoff] = (bf16)0.0f; qr[qoff] = (bf16)0.0f;
    kkb[qoff] = (bf16)0.0f; vT[voff] = (bf16)0.0f;
  }
}

// ---------------- rk repack: rkall fp32 [rows][nl*768] -> rkb bf16 [l][n][TPM][64] ----------------
__global__ void k_rkrepack(const float* __restrict__ rkall, bf16* __restrict__ rkb,
                           int T, int Ncols, int l0) {
  const int i = blockIdx.x, z = blockIdx.y, d = threadIdx.x;  // block = 768
  const float v = (i < T) ? rkall[(long)i * Ncols + z * ED + d] : 0.0f;
  const int n = d >> 6, dh = d & 63;
  rkb[(((long)(l0 + z) * NH + n) * TPM + i) * 64 + dh] = (bf16)v;
}

// ---------------- AC scores: S[i][j] = SCL * (q+rwb)_i . k_j ----------------
__global__ __launch_bounds__(64) void k_scoreAC(const bf16* __restrict__ qw,
                                                const bf16* __restrict__ kkb,
                                                float* __restrict__ S) {
  const int ti = blockIdx.x, tj = blockIdx.y, bh = blockIdx.z;
  const int l = threadIdx.x;
  const bf16* Ap = qw + (long)bh * TPM * 64 + (ti * 16 + (l & 15)) * 64 + 8 * (l >> 4);
  const bf16* Bp = kkb + (long)bh * TPM * 64 + (tj * 16 + (l & 15)) * 64 + 8 * (l >> 4);
  f32x4 c = {};
  c = __builtin_amdgcn_mfma_f32_16x16x32_bf16(*(const bf16x8*)Ap, *(const bf16x8*)Bp, c, 0, 0, 0);
  c = __builtin_amdgcn_mfma_f32_16x16x32_bf16(*(const bf16x8*)(Ap + 32), *(const bf16x8*)(Bp + 32), c, 0, 0, 0);
  float* outp = S + (long)bh * TPM * TPM;
  const int col = tj * 16 + (l & 15);
  const int rb = ti * 16 + 4 * (l >> 4);
#pragma unroll
  for (int r = 0; r < 4; ++r) outp[(long)(rb + r) * TPM + col] = SCL * c[r];
}

// ---------------- BD scores with rel_shift applied at write (scatter-add) ----------------
// BDraw[a][b] lands at m = a*(T+1)+b+1; if m>=T: i=m/T-1, j=m-(i+1)*T; S[i][j] += SCL*val.
// Bijective onto {j != i+1}; diagonal j=i+1 keeps bd=0 (matches reference zero-pad).
__global__ __launch_bounds__(64) void k_scoreBD(const bf16* __restrict__ qr,
                                                const bf16* __restrict__ rkb_l,
                                                float* __restrict__ S, int T) {
  const int ti = blockIdx.x, tj = blockIdx.y, bh = blockIdx.z;
  const int l = threadIdx.x;
  const bf16* Ap = qr + (long)bh * TPM * 64 + (ti * 16 + (l & 15)) * 64 + 8 * (l >> 4);
  const bf16* Bp = rkb_l + (long)(bh % NH) * TPM * 64 + (tj * 16 + (l & 15)) * 64 + 8 * (l >> 4);
  f32x4 c = {};
  c = __builtin_amdgcn_mfma_f32_16x16x32_bf16(*(const bf16x8*)Ap, *(const bf16x8*)Bp, c, 0, 0, 0);
  c = __builtin_amdgcn_mfma_f32_16x16x32_bf16(*(const bf16x8*)(Ap + 32), *(const bf16x8*)(Bp + 32), c, 0, 0, 0);
  float* Sb = S + (long)bh * TPM * TPM;
  const int b = tj * 16 + (l & 15);
  const int ab = ti * 16 + 4 * (l >> 4);
#pragma unroll
  for (int r = 0; r < 4; ++r) {
    const int a = ab + r;
    if (a < T && b < T) {
      const int m = a * (T + 1) + b + 1;
      if (m >= T) {
        const int i = m / T - 1;
        const int j = m - (i + 1) * T;
        Sb[(long)i * TPM + j] += SCL * c[r];
      }
    }
  }
}

// ---------------- softmax over fused scores ----------------
__global__ __launch_bounds__(256) void k_softmax(const float* __restrict__ S,
                                                 bf16* __restrict__ prob, int T, int KPV) {
  const int i = blockIdx.x, bh = blockIdx.y, tid = threadIdx.x;
  bf16* prow = prob + (long)bh * TPM * KPM + (long)i * KPM;
  if (i >= T) {  // clean padded rows (uniform per block)
    for (int c = tid; c < KPV; c += 256) prow[c] = (bf16)0.0f;
    return;
  }
  const float* srow = S + (long)bh * TPM * TPM + (long)i * TPM;
  float val = -3.0e38f;
  if (tid < T) val = srow[tid];
  __shared__ float red[8];
  float mx = val;
#pragma unroll
  for (int o = 32; o; o >>= 1) mx = fmaxf(mx, __shfl_xor(mx, o));
  if ((tid & 63) == 0) red[tid >> 6] = mx;
  __syncthreads();
  mx = fmaxf(fmaxf(red[0], red[1]), fmaxf(red[2], red[3]));
  const float e = (tid < T) ? expf(val - mx) : 0.0f;
  float sm = e;
#pragma unroll
  for (int o = 32; o; o >>= 1) sm += __shfl_xor(sm, o);
  if ((tid & 63) == 0) red[4 + (tid >> 6)] = sm;
  __syncthreads();
  sm = red[4] + red[5] + red[6] + red[7];
  if (tid < KPV) prow[tid] = (tid < T) ? (bf16)(e / sm) : (bf16)0.0f;
}

// ---------------- PV: av[i,d] = sum_j prob[i,j] * v[j,d] ----------------
__global__ __launch_bounds__(64) void k_pv(const bf16* __restrict__ prob, const bf16* __restrict__ vT,
                                           bf16* __restrict__ avb, int T, int KPV) {
  const int ti = blockIdx.x, dj = blockIdx.y, bh = blockIdx.z;
  const int l = threadIdx.x;
  const int b = bh / NH, n = bh % NH;
  const bf16* Ap = prob + (long)bh * TPM * KPM + (ti * 16 + (l & 15)) * KPM + 8 * (l >> 4);
  const bf16* Bp = vT + (long)bh * 64 * KPM + (dj * 16 + (l & 15)) * KPM + 8 * (l >> 4);
  f32x4 c = {};
  for (int s = 0; s < KPV; s += 32)
    c = __builtin_amdgcn_mfma_f32_16x16x32_bf16(*(const bf16x8*)(Ap + s), *(const bf16x8*)(Bp + s), c, 0, 0, 0);
  const int d = dj * 16 + (l & 15);
  const int ib = ti * 16 + 4 * (l >> 4);
#pragma unroll
  for (int r = 0; r < 4; ++r) {
    const int i = ib + r;
    if (i < T) avb[((long)(i * NB + b)) * ED + n * 64 + d] = (bf16)c[r];
  }
}

// ---------------- residual + LayerNorm (fp32 master, bf16 copy) ----------------
__global__ __launch_bounds__(256) void k_ln(const float* __restrict__ xin, const float* __restrict__ add,
                                            const float* __restrict__ g, const float* __restrict__ bb,
                                            float* __restrict__ xo, bf16* __restrict__ xbo, int Mreal) {
  const int row = blockIdx.x, tid = threadIdx.x;
  const long base = (long)row * ED;
  __shared__ float red[4];
  if (row >= Mreal) {
#pragma unroll
    for (int e = 0; e < 3; ++e) { xo[base + tid + e * 256] = 0.0f; xbo[base + tid + e * 256] = (bf16)0.0f; }
    return;
  }
  float v[3];
#pragma unroll
  for (int e = 0; e < 3; ++e) v[e] = xin[base + tid + e * 256] + add[base + tid + e * 256];
  const float mean = block_sum(v[0] + v[1] + v[2], red, tid) * (1.0f / ED);
  float sq = 0.0f;
#pragma unroll
  for (int e = 0; e < 3; ++e) { const float dd = v[e] - mean; sq += dd * dd; }
  const float var = block_sum(sq, red, tid) * (1.0f / ED);
  const float rs = rsqrtf(var + 1e-5f);
#pragma unroll
  for (int e = 0; e < 3; ++e) {
    const int c = tid + e * 256;
    const float o = (v[e] - mean) * rs * g[c] + bb[c];
    xo[base + c] = o;
    xbo[base + c] = (bf16)o;
  }
}

// ---------------- downsample: segment-mean pool + null token + LN ----------------
// Reference segmentation (seg = cumsum(bnd)-bnd, bnd at t%5==0):
//   seg 0 = {0}; seg s (1..39) = {5s-4 .. 5s}. Output row 0 = null token, row 1+s = seg s.
__global__ __launch_bounds__(256) void k_down(const float* __restrict__ x, const float* __restrict__ nullt,
                                              const float* __restrict__ g, const float* __restrict__ bb,
                                              float* __restrict__ xo, bf16* __restrict__ xbo) {
  const int row = blockIdx.x, tid = threadIdx.x;
  const long base = (long)row * ED;
  __shared__ float red[4];
  if (row >= TT2 * NB) {
#pragma unroll
    for (int e = 0; e < 3; ++e) { xo[base + tid + e * 256] = 0.0f; xbo[base + tid + e * 256] = (bf16)0.0f; }
    return;
  }
  const int s = row >> 5, b = row & 31;
  float v[3];
  if (s == 0) {
#pragma unroll
    for (int e = 0; e < 3; ++e) v[e] = nullt[tid + e * 256];
  } else {
    const int seg = s - 1;
    const int t0 = (seg == 0) ? 0 : (5 * seg - 4);
    const int cnt = (seg == 0) ? 1 : 5;
#pragma unroll
    for (int e = 0; e < 3; ++e) {
      float a = 0.0f;
      for (int tt = 0; tt < cnt; ++tt) a += x[((long)((t0 + tt) * NB + b)) * ED + tid + e * 256];
      v[e] = a / (float)cnt;
    }
  }
  const float mean = block_sum(v[0] + v[1] + v[2], red, tid) * (1.0f / ED);
  float sq = 0.0f;
#pragma unroll
  for (int e = 0; e < 3; ++e) { const float dd = v[e] - mean; sq += dd * dd; }
  const float var = block_sum(sq, red, tid) * (1.0f / ED);
  const float rs = rsqrtf(var + 1e-5f);
#pragma unroll
  for (int e = 0; e < 3; ++e) {
    const int c = tid + e * 256;
    const float o = (v[e] - mean) * rs * g[c] + bb[c];
    xo[base + c] = o;
    xbo[base + c] = (bf16)o;
  }
}

// ---------------- final token mean (fp32) ----------------
__global__ __launch_bounds__(256) void k_mean(const float* __restrict__ x2, float* __restrict__ xm) {
  const int b = blockIdx.x, tid = threadIdx.x;
#pragma unroll
  for (int e = 0; e < 3; ++e) {
    const int c = tid + e * 256;
    float a = 0.0f;
    for (int s = 0; s < TT2; ++s) a += x2[((long)(s * NB + b)) * ED + c];
    xm[(long)b * ED + c] = a * (1.0f / TT2);
  }
}

// ---------------- classifier head (fp32 dot, wave per (b,n)) ----------------
__global__ __launch_bounds__(256) void k_head(const float* __restrict__ xm, const float* __restrict__ hw,
                                              const float* __restrict__ hbias, float* __restrict__ out) {
  const int gid = blockIdx.x * 4 + (threadIdx.x >> 6);
  const int l = threadIdx.x & 63;
  if (gid >= NB * 1000) return;
  const int b = gid / 1000, n = gid % 1000;
  const float* xr = xm + (long)b * ED;
  const float* wr = hw + (long)n * ED;
  float a = 0.0f;
#pragma unroll
  for (int e = 0; e < 12; ++e) a += xr[l + 64 * e] * wr[l + 64 * e];
#pragma unroll
  for (int o = 32; o; o >>= 1) a += __shfl_xor(a, o);
  if (l == 0) out[(long)b * 1000 + n] = a + hbias[n];
}

// =======================================================================
extern "C" void kernel_launch(void* const* d_in, const int* in_sizes, int n_in,
                              void* d_out, int out_size, void* d_ws, size_t ws_size,
                              hipStream_t stream) {
  const float* in_x     = (const float*)d_in[0];
  const float* patch_w  = (const float*)d_in[1];
  const float* patch_b  = (const float*)d_in[2];
  const float* r_w_bias = (const float*)d_in[3];
  const float* r_r_bias = (const float*)d_in[4];
  const float* qkv_w    = (const float*)d_in[5];
  const float* qkv_b    = (const float*)d_in[6];
  const float* rnet_w   = (const float*)d_in[7];
  const float* rnet_b   = (const float*)d_in[8];
  const float* onet_w   = (const float*)d_in[9];
  const float* onet_b   = (const float*)d_in[10];
  const float* ln1_g    = (const float*)d_in[11];
  const float* ln1_b    = (const float*)d_in[12];
  const float* ff1_w    = (const float*)d_in[13];
  const float* ff1_b    = (const float*)d_in[14];
  const float* ff2_w    = (const float*)d_in[15];
  const float* ff2_b    = (const float*)d_in[16];
  const float* ln2_g    = (const float*)d_in[17];
  const float* ln2_b    = (const float*)d_in[18];
  const float* null_tok = (const float*)d_in[19];
  const float* down_g   = (const float*)d_in[20];
  const float* down_b   = (const float*)d_in[21];
  const float* head_w   = (const float*)d_in[22];
  const float* head_b   = (const float*)d_in[23];
  float* out = (float*)d_out;

  // ---- workspace layout: lifetime-unioned arenas, ~189 MB total ----
  char* base = (char*)d_ws;
  size_t off = 0;
  auto take = [&](size_t bytes) -> char* {
    char* r = base + off;
    off += (bytes + 255) & ~(size_t)255;
    return r;
  };

  // persistent
  float* x    = (float*)take((size_t)MM1 * ED * 4);
  bf16*  xb   = (bf16*)take((size_t)MM1 * ED * 2);
  float* x2   = (float*)take((size_t)MM2 * ED * 4);
  bf16*  xb2  = (bf16*)take((size_t)MM2 * ED * 2);
  bf16*  rkb  = (bf16*)take((size_t)LTOT * NH * TPM * 64 * 2);
  bf16*  rbf  = (bf16*)take((size_t)256 * ED * 2);
  bf16*  r2bf = (bf16*)take((size_t)128 * ED * 2);
  float* xm   = (float*)take((size_t)NB * ED * 4);

  // Arena W: per-layer weights; setup overlay = wrnet(11.8M)+wpatch(1.2M)
  char* arenaW = take((size_t)(2304 * 768 + 768 * 768 + 3072 * 768 + 768 * 3072) * 2);
  bf16* wq = (bf16*)arenaW;
  bf16* wo = wq + (size_t)2304 * 768;
  bf16* w1 = wo + (size_t)768 * 768;
  bf16* w2 = w1 + (size_t)3072 * 768;
  bf16* wrnet  = (bf16*)arenaW;                       // setup only
  bf16* wpatch = wrnet + (size_t)LTOT * 768 * 768;    // setup only

  // Arena Q: attention operand tiles; setup overlay = A0 (im2col, 9.6M)
  char* arenaQ = take((size_t)(3 * TPM * 64 + 64 * KPM) * BHN * 2);
  bf16* qw  = (bf16*)arenaQ;
  bf16* qr  = qw + (size_t)BHN * TPM * 64;
  bf16* kkb = qr + (size_t)BHN * TPM * 64;
  bf16* vT  = kkb + (size_t)BHN * TPM * 64;
  bf16* A0  = (bf16*)arenaQ;                          // setup only

  // Arena H: heads(bf16, 28.9M) then prob(35.8M); setup overlay = rkall1+rkall2
  char* arenaH = take((size_t)BHN * TPM * KPM * 2);
  bf16*  headsb = (bf16*)arenaH;
  bf16*  prob   = (bf16*)arenaH;
  float* rkall1 = (float*)arenaH;                     // setup only (1.6M)
  float* rkall2 = (float*)(arenaH + (size_t)256 * 1536 * 4);  // setup only (3.1M)

  // Arena S: scores S (fp32, 66.5M) then {avb, gout, hb} (67.4M)
  char* arenaS = take((size_t)MM1 * ED * 2 + (size_t)MM1 * ED * 4 + (size_t)MM1 * FFD * 2);
  float* S    = (float*)arenaS;
  bf16*  avb  = (bf16*)arenaS;
  float* gout = (float*)(arenaS + (size_t)MM1 * ED * 2);
  bf16*  hb   = (bf16*)(arenaS + (size_t)MM1 * ED * 2 + (size_t)MM1 * ED * 4);

  if (off > ws_size) return;  // diagnostic: ws too small -> clean absmax fail, not a fault

  // ---- setup: pos embeddings, weight conversions, patch embed, rk ----
  k_posemb<<<dim3(256), dim3(768), 0, stream>>>(rbf, TT1);
  k_posemb<<<dim3(128), dim3(768), 0, stream>>>(r2bf, TT2);
  k_cvt<<<dim3(2048), dim3(256), 0, stream>>>(rnet_w, wrnet, (long)LTOT * 768 * 768);
  k_cvt<<<dim3(1024), dim3(256), 0, stream>>>(patch_w, wpatch, (long)768 * 768);
  k_im2col<<<dim3((MM1 * ED + 255) / 256), dim3(256), 0, stream>>>(in_x, A0);
  k_gemm<2><<<dim3(6, 49), dim3(256), 0, stream>>>(A0, wpatch, patch_b, x, xb, MM1, ED, ED);
  k_gemm<0><<<dim3(12, 2), dim3(256), 0, stream>>>(rbf, wrnet, rnet_b, rkall1, nullptr, 256, 1536, ED);
  k_gemm<0><<<dim3(48, 1), dim3(256), 0, stream>>>(r2bf, wrnet + (size_t)2 * 768 * 768, rnet_b + 2 * 768,
                                                   rkall2, nullptr, 128, 6144, ED);
  k_rkrepack<<<dim3(TPM, 2), dim3(768), 0, stream>>>(rkall1, rkb, TT1, 1536, 0);
  k_rkrepack<<<dim3(48, 8), dim3(768), 0, stream>>>(rkall2, rkb, TT2, 6144, 2);

  // ---- transformer layers ----
  for (int l = 0; l < LTOT; ++l) {
    const bool pre = (l < 2);
    const int T = pre ? TT1 : TT2;
    const int TPu = pre ? TPM : 48;   // padded token count in use
    const int KPV = pre ? KPM : 64;   // padded PV K dim in use
    const int Mp = pre ? MM1 : MM2;
    const int Mreal = pre ? MM1 : M2R;
    float* xcur = pre ? x : x2;
    bf16* xbcur = pre ? xb : xb2;

    k_cvt4<<<dim3(2048), dim3(256), 0, stream>>>(
        qkv_w + (size_t)l * 2304 * 768, onet_w + (size_t)l * 768 * 768,
        ff1_w + (size_t)l * 3072 * 768, ff2_w + (size_t)l * 768 * 3072,
        wq, wo, w1, w2, 2304 * 768, 768 * 768, 3072 * 768, 768 * 3072);

    k_gemm<3><<<dim3(18, Mp / 128), dim3(256), 0, stream>>>(xbcur, wq, qkv_b + (size_t)l * 2304,
                                                            nullptr, headsb, Mp, 3 * ED, ED);
    k_repack<<<dim3(TPu, BHN), dim3(64), 0, stream>>>(headsb, r_w_bias, r_r_bias, qw, qr, kkb, vT, T);
    k_scoreAC<<<dim3(TPu / 16, TPu / 16, BHN), dim3(64), 0, stream>>>(qw, kkb, S);
    k_scoreBD<<<dim3(TPu / 16, TPu / 16, BHN), dim3(64), 0, stream>>>(
        qr, rkb + (size_t)l * NH * TPM * 64, S, T);
    k_softmax<<<dim3(TPu, BHN), dim3(256), 0, stream>>>(S, prob, T, KPV);
    k_pv<<<dim3(TPu / 16, 4, BHN), dim3(64), 0, stream>>>(prob, vT, avb, T, KPV);
    k_gemm<0><<<dim3(6, Mp / 128), dim3(256), 0, stream>>>(avb, wo, onet_b + (size_t)l * 768,
                                                           gout, nullptr, Mp, ED, ED);
    k_ln<<<dim3(Mp), dim3(256), 0, stream>>>(xcur, gout, ln1_g + (size_t)l * 768, ln1_b + (size_t)l * 768,
                                             xcur, xbcur, Mreal);
    k_gemm<1><<<dim3(24, Mp / 128), dim3(256), 0, stream>>>(xbcur, w1, ff1_b + (size_t)l * 3072,
                                                            nullptr, hb, Mp, FFD, ED);
    k_gemm<0><<<dim3(6, Mp / 128), dim3(256), 0, stream>>>(hb, w2, ff2_b + (size_t)l * 768,
                                                           gout, nullptr, Mp, ED, FFD);
    k_ln<<<dim3(Mp), dim3(256), 0, stream>>>(xcur, gout, ln2_g + (size_t)l * 768, ln2_b + (size_t)l * 768,
                                             xcur, xbcur, Mreal);

    if (l == 1) {  // pool 196 -> {null} + 40 segments, LN -> short-stack input
      k_down<<<dim3(MM2), dim3(256), 0, stream>>>(x, null_tok, down_g, down_b, x2, xb2);
    }
  }

  // ---- final: token mean + classifier head (fp32) ----
  k_mean<<<dim3(NB), dim3(256), 0, stream>>>(x2, xm);
  k_head<<<dim3(8000), dim3(256), 0, stream>>>(xm, head_w, head_b, out);
}

// Round 3
// 2578.801 us; speedup vs baseline: 1.0382x; 1.0382x over previous
//
#include <hip/hip_runtime.h>
#include <hip/hip_bf16.h>
#include <math.h>
#include <stdint.h>

// ---------------- types ----------------
typedef __bf16 bf16;
typedef __bf16 bf16x8 __attribute__((ext_vector_type(8)));
typedef float  f32x4  __attribute__((ext_vector_type(4)));

// ---------------- model constants ----------------
#define NB   32        // batch
#define ED   768       // embed dim
#define NH   12        // heads
#define DHD  64        // head dim
#define FFD  3072
#define TT1  196       // pre-stack tokens
#define TT2  41        // short-stack tokens
#define TPM  208       // padded token dim (row stride for q/k/rk/S/prob)
#define KPM  224       // padded K dim for PV (col stride for prob/vT)
#define MM1  6272      // 196*32  (= 49*128)
#define MM2  1408      // padded 41*32=1312 -> 11*128
#define M2R  1312
#define BHN  384       // 32*12
#define LTOT 10
#define SCL  0.125f    // 1/sqrt(64)

// ---------------- async global->LDS (16B per lane, wave-uniform LDS base) ----------------
__device__ __forceinline__ void gload_lds16(const bf16* g, bf16* l) {
  __builtin_amdgcn_global_load_lds(
      (__attribute__((address_space(1))) void*)(uintptr_t)g,
      (__attribute__((address_space(3))) void*)(uint32_t)(uintptr_t)l,
      16, 0, 0);
}

// ---------------- helpers ----------------
__device__ __forceinline__ float block_sum(float v, float* red, int tid) {
#pragma unroll
  for (int o = 32; o; o >>= 1) v += __shfl_xor(v, o);
  if ((tid & 63) == 0) red[tid >> 6] = v;
  __syncthreads();
  float t = red[0] + red[1] + red[2] + red[3];
  __syncthreads();
  return t;
}

__device__ __forceinline__ bf16x8 cvt8(const float* __restrict__ s) {
  const f32x4 a = *(const f32x4*)s;
  const f32x4 b = *(const f32x4*)(s + 4);
  bf16x8 o;
#pragma unroll
  for (int j = 0; j < 4; ++j) { o[j] = (bf16)a[j]; o[4 + j] = (bf16)b[j]; }
  return o;
}

// ---------------- fp32 -> bf16 converters (vectorized, n % 8 == 0) ----------------
__global__ void k_cvt(const float* __restrict__ s, bf16* __restrict__ d, long n8) {
  for (long i = (long)blockIdx.x * 256 + threadIdx.x; i < n8; i += (long)gridDim.x * 256)
    *(bf16x8*)&d[i * 8] = cvt8(&s[i * 8]);
}

__global__ void k_cvt4(const float* __restrict__ a, const float* __restrict__ b,
                       const float* __restrict__ c, const float* __restrict__ d,
                       bf16* __restrict__ oa, bf16* __restrict__ ob,
                       bf16* __restrict__ oc, bf16* __restrict__ od,
                       int na8, int nb8, int nc8, int nd8) {
  const long tot = (long)na8 + nb8 + nc8 + nd8;
  for (long i = (long)blockIdx.x * 256 + threadIdx.x; i < tot; i += (long)gridDim.x * 256) {
    if (i < na8) *(bf16x8*)&oa[i * 8] = cvt8(&a[i * 8]);
    else if (i < (long)na8 + nb8) { const long j = i - na8; *(bf16x8*)&ob[j * 8] = cvt8(&b[j * 8]); }
    else if (i < (long)na8 + nb8 + nc8) { const long j = i - na8 - nb8; *(bf16x8*)&oc[j * 8] = cvt8(&c[j * 8]); }
    else { const long j = i - na8 - nb8 - nc8; *(bf16x8*)&od[j * 8] = cvt8(&d[j * 8]); }
  }
}

// ---------------- sinusoidal pos emb (descending pos), bf16 out ----------------
__global__ void k_posemb(bf16* __restrict__ out, int T) {
  const int t = blockIdx.x, c = threadIdx.x;   // block = 768
  float v = 0.0f;
  if (t < T) {
    const float pos = (float)(T - 1 - t);
    const int ci = (c < 384) ? c : c - 384;
    const float invf = expf(-(float)ci * (9.210340371976184f / 384.0f)); // ln(10000)
    const float a = pos * invf;
    v = (c < 384) ? sinf(a) : cosf(a);
  }
  out[(long)t * ED + c] = (bf16)v;
}

// ---------------- im2col for patch embed: A0[t*32+b][c*256+i*16+j] ----------------
__global__ void k_im2col(const float* __restrict__ x, bf16* __restrict__ A0) {
  const long idx = (long)blockIdx.x * 256 + threadIdx.x;
  if (idx >= (long)MM1 * ED) return;
  const int row = (int)(idx / ED), k = (int)(idx % ED);
  const int t = row >> 5, b = row & 31;
  const int c = k >> 8, rem = k & 255, i = rem >> 4, j = rem & 15;
  const int py = t / 14, px = t % 14;
  A0[idx] = (bf16)x[((long)(b * 3 + c) * 224 + (py * 16 + i)) * 224 + px * 16 + j];
}

// ---------------- GEMM: C[m,n] = sum_k A[m,k]*B[n,k] + bias[n] ----------------
// 128x128 tile, BK=64, 4 waves, global_load_lds dwordx4 staging (m97 structure).
// EPI: 0=fp32; 1=GELU->bf16; 2=fp32+bf16; 3=bf16. Requires M%128==0, N%128==0, K%64==0.
template <int EPI>
__global__ __launch_bounds__(256) void k_gemm(const bf16* __restrict__ A, const bf16* __restrict__ Bw,
                                              const float* __restrict__ bias,
                                              float* __restrict__ Cf, bf16* __restrict__ Cb,
                                              int M, int N, int K) {
  __shared__ __align__(16) bf16 As[128 * 64];
  __shared__ __align__(16) bf16 Bs[128 * 64];
  const int tid = threadIdx.x;
  const int l = tid & 63, w = tid >> 6;
  const int wr = w >> 1, wc = w & 1;
  const int m0 = blockIdx.y * 128, n0 = blockIdx.x * 128;
  const int lrow = l >> 3;            // 0..7 within an 8-row chunk
  const int lcol = (l & 7) * 8;       // 0..56, 8 bf16 = 16B per lane
  f32x4 acc[4][4] = {};
  for (int k0 = 0; k0 < K; k0 += 64) {
    __syncthreads();
#pragma unroll
    for (int p = 0; p < 4; ++p) {
      const int rbase = w * 32 + p * 8;               // wave-uniform
      gload_lds16(&A[(long)(m0 + rbase + lrow) * K + k0 + lcol], &As[rbase * 64]);
      gload_lds16(&Bw[(long)(n0 + rbase + lrow) * K + k0 + lcol], &Bs[rbase * 64]);
    }
    __syncthreads();   // compiler drains vmcnt before barrier
#pragma unroll
    for (int kk = 0; kk < 64; kk += 32) {
      bf16x8 af[4], bg[4];
#pragma unroll
      for (int m = 0; m < 4; ++m)
        af[m] = *(const bf16x8*)&As[(wr * 64 + m * 16 + (l & 15)) * 64 + kk + 8 * (l >> 4)];
#pragma unroll
      for (int n = 0; n < 4; ++n)
        bg[n] = *(const bf16x8*)&Bs[(wc * 64 + n * 16 + (l & 15)) * 64 + kk + 8 * (l >> 4)];
#pragma unroll
      for (int m = 0; m < 4; ++m)
#pragma unroll
        for (int n = 0; n < 4; ++n)
          acc[m][n] = __builtin_amdgcn_mfma_f32_16x16x32_bf16(af[m], bg[n], acc[m][n], 0, 0, 0);
    }
  }
#pragma unroll
  for (int m = 0; m < 4; ++m) {
    const int row = m0 + wr * 64 + m * 16 + 4 * (l >> 4);
#pragma unroll
    for (int n = 0; n < 4; ++n) {
      const int col = n0 + wc * 64 + n * 16 + (l & 15);
      const float bv = bias[col];
#pragma unroll
      for (int r = 0; r < 4; ++r) {
        const float v = acc[m][n][r] + bv;
        const long off = (long)(row + r) * N + col;
        if (EPI == 0) {
          Cf[off] = v;
        } else if (EPI == 1) {
          Cb[off] = (bf16)(0.5f * v * (1.0f + erff(v * 0.70710678118654752f)));
        } else if (EPI == 2) {
          Cf[off] = v;
          Cb[off] = (bf16)v;
        } else {
          Cb[off] = (bf16)v;
        }
      }
    }
  }
}

// ---------------- repack qkv heads -> attention layouts ----------------
// qw/qr/kk: [bh][TPM][64] bf16 (rows >= T zeroed). vT: [bh][64][KPM] bf16.
__global__ void k_repack(const bf16* __restrict__ heads, const float* __restrict__ rwb,
                         const float* __restrict__ rrb,
                         bf16* __restrict__ qw, bf16* __restrict__ qr,
                         bf16* __restrict__ kkb, bf16* __restrict__ vT, int T) {
  const int i = blockIdx.x, bh = blockIdx.y, d = threadIdx.x;  // block = 64
  const int b = bh / NH, n = bh % NH;
  const long qoff = (long)bh * TPM * 64 + (long)i * 64 + d;
  const long voff = (long)bh * 64 * KPM + (long)d * KPM + i;
  if (i < T) {
    const long src = ((long)(i * NB + b)) * (3 * ED) + n * 64 + d;
    const float q = (float)heads[src];
    qw[qoff] = (bf16)(q + rwb[n * 64 + d]);
    qr[qoff] = (bf16)(q + rrb[n * 64 + d]);
    kkb[qoff] = heads[src + ED];
    vT[voff] = heads[src + 2 * ED];
  } else {
    qw[qoff] = (bf16)0.0f; qr[qoff] = (bf16)0.0f;
    kkb[qoff] = (bf16)0.0f; vT[voff] = (bf16)0.0f;
  }
}

// ---------------- rk repack: rkall fp32 [rows][nl*768] -> rkb bf16 [l][n][TPM][64] ----------------
__global__ void k_rkrepack(const float* __restrict__ rkall, bf16* __restrict__ rkb,
                           int T, int Ncols, int l0) {
  const int i = blockIdx.x, z = blockIdx.y, d = threadIdx.x;  // block = 768
  const float v = (i < T) ? rkall[(long)i * Ncols + z * ED + d] : 0.0f;
  const int n = d >> 6, dh = d & 63;
  rkb[(((long)(l0 + z) * NH + n) * TPM + i) * 64 + dh] = (bf16)v;
}

// ---------------- AC scores: S[i][j] = SCL * (q+rwb)_i . k_j ----------------
__global__ __launch_bounds__(64) void k_scoreAC(const bf16* __restrict__ qw,
                                                const bf16* __restrict__ kkb,
                                                float* __restrict__ S) {
  const int ti = blockIdx.x, tj = blockIdx.y, bh = blockIdx.z;
  const int l = threadIdx.x;
  const bf16* Ap = qw + (long)bh * TPM * 64 + (ti * 16 + (l & 15)) * 64 + 8 * (l >> 4);
  const bf16* Bp = kkb + (long)bh * TPM * 64 + (tj * 16 + (l & 15)) * 64 + 8 * (l >> 4);
  f32x4 c = {};
  c = __builtin_amdgcn_mfma_f32_16x16x32_bf16(*(const bf16x8*)Ap, *(const bf16x8*)Bp, c, 0, 0, 0);
  c = __builtin_amdgcn_mfma_f32_16x16x32_bf16(*(const bf16x8*)(Ap + 32), *(const bf16x8*)(Bp + 32), c, 0, 0, 0);
  float* outp = S + (long)bh * TPM * TPM;
  const int col = tj * 16 + (l & 15);
  const int rb = ti * 16 + 4 * (l >> 4);
#pragma unroll
  for (int r = 0; r < 4; ++r) outp[(long)(rb + r) * TPM + col] = SCL * c[r];
}

// ---------------- BD scores with rel_shift applied at write (scatter-add) ----------------
// BDraw[a][b] lands at m = a*(T+1)+b+1; if m>=T: i=m/T-1, j=m-(i+1)*T; S[i][j] += SCL*val.
// Bijective onto {j != i+1}; diagonal j=i+1 keeps bd=0 (matches reference zero-pad).
__global__ __launch_bounds__(64) void k_scoreBD(const bf16* __restrict__ qr,
                                                const bf16* __restrict__ rkb_l,
                                                float* __restrict__ S, int T) {
  const int ti = blockIdx.x, tj = blockIdx.y, bh = blockIdx.z;
  const int l = threadIdx.x;
  const bf16* Ap = qr + (long)bh * TPM * 64 + (ti * 16 + (l & 15)) * 64 + 8 * (l >> 4);
  const bf16* Bp = rkb_l + (long)(bh % NH) * TPM * 64 + (tj * 16 + (l & 15)) * 64 + 8 * (l >> 4);
  f32x4 c = {};
  c = __builtin_amdgcn_mfma_f32_16x16x32_bf16(*(const bf16x8*)Ap, *(const bf16x8*)Bp, c, 0, 0, 0);
  c = __builtin_amdgcn_mfma_f32_16x16x32_bf16(*(const bf16x8*)(Ap + 32), *(const bf16x8*)(Bp + 32), c, 0, 0, 0);
  float* Sb = S + (long)bh * TPM * TPM;
  const int b = tj * 16 + (l & 15);
  const int ab = ti * 16 + 4 * (l >> 4);
#pragma unroll
  for (int r = 0; r < 4; ++r) {
    const int a = ab + r;
    if (a < T && b < T) {
      const int m = a * (T + 1) + b + 1;
      if (m >= T) {
        const int i = m / T - 1;
        const int j = m - (i + 1) * T;
        Sb[(long)i * TPM + j] += SCL * c[r];
      }
    }
  }
}

// ---------------- softmax over fused scores ----------------
__global__ __launch_bounds__(256) void k_softmax(const float* __restrict__ S,
                                                 bf16* __restrict__ prob, int T, int KPV) {
  const int i = blockIdx.x, bh = blockIdx.y, tid = threadIdx.x;
  bf16* prow = prob + (long)bh * TPM * KPM + (long)i * KPM;
  if (i >= T) {  // clean padded rows (uniform per block)
    for (int c = tid; c < KPV; c += 256) prow[c] = (bf16)0.0f;
    return;
  }
  const float* srow = S + (long)bh * TPM * TPM + (long)i * TPM;
  float val = -3.0e38f;
  if (tid < T) val = srow[tid];
  __shared__ float red[8];
  float mx = val;
#pragma unroll
  for (int o = 32; o; o >>= 1) mx = fmaxf(mx, __shfl_xor(mx, o));
  if ((tid & 63) == 0) red[tid >> 6] = mx;
  __syncthreads();
  mx = fmaxf(fmaxf(red[0], red[1]), fmaxf(red[2], red[3]));
  const float e = (tid < T) ? expf(val - mx) : 0.0f;
  float sm = e;
#pragma unroll
  for (int o = 32; o; o >>= 1) sm += __shfl_xor(sm, o);
  if ((tid & 63) == 0) red[4 + (tid >> 6)] = sm;
  __syncthreads();
  sm = red[4] + red[5] + red[6] + red[7];
  if (tid < KPV) prow[tid] = (tid < T) ? (bf16)(e / sm) : (bf16)0.0f;
}

// ---------------- PV: av[i,d] = sum_j prob[i,j] * v[j,d] ----------------
__global__ __launch_bounds__(64) void k_pv(const bf16* __restrict__ prob, const bf16* __restrict__ vT,
                                           bf16* __restrict__ avb, int T, int KPV) {
  const int ti = blockIdx.x, dj = blockIdx.y, bh = blockIdx.z;
  const int l = threadIdx.x;
  const int b = bh / NH, n = bh % NH;
  const bf16* Ap = prob + (long)bh * TPM * KPM + (ti * 16 + (l & 15)) * KPM + 8 * (l >> 4);
  const bf16* Bp = vT + (long)bh * 64 * KPM + (dj * 16 + (l & 15)) * KPM + 8 * (l >> 4);
  f32x4 c = {};
  for (int s = 0; s < KPV; s += 32)
    c = __builtin_amdgcn_mfma_f32_16x16x32_bf16(*(const bf16x8*)(Ap + s), *(const bf16x8*)(Bp + s), c, 0, 0, 0);
  const int d = dj * 16 + (l & 15);
  const int ib = ti * 16 + 4 * (l >> 4);
#pragma unroll
  for (int r = 0; r < 4; ++r) {
    const int i = ib + r;
    if (i < T) avb[((long)(i * NB + b)) * ED + n * 64 + d] = (bf16)c[r];
  }
}

// ---------------- residual + LayerNorm (fp32 master, bf16 copy) ----------------
__global__ __launch_bounds__(256) void k_ln(const float* __restrict__ xin, const float* __restrict__ add,
                                            const float* __restrict__ g, const float* __restrict__ bb,
                                            float* __restrict__ xo, bf16* __restrict__ xbo, int Mreal) {
  const int row = blockIdx.x, tid = threadIdx.x;
  const long base = (long)row * ED;
  __shared__ float red[4];
  if (row >= Mreal) {
#pragma unroll
    for (int e = 0; e < 3; ++e) { xo[base + tid + e * 256] = 0.0f; xbo[base + tid + e * 256] = (bf16)0.0f; }
    return;
  }
  float v[3];
#pragma unroll
  for (int e = 0; e < 3; ++e) v[e] = xin[base + tid + e * 256] + add[base + tid + e * 256];
  const float mean = block_sum(v[0] + v[1] + v[2], red, tid) * (1.0f / ED);
  float sq = 0.0f;
#pragma unroll
  for (int e = 0; e < 3; ++e) { const float dd = v[e] - mean; sq += dd * dd; }
  const float var = block_sum(sq, red, tid) * (1.0f / ED);
  const float rs = rsqrtf(var + 1e-5f);
#pragma unroll
  for (int e = 0; e < 3; ++e) {
    const int c = tid + e * 256;
    const float o = (v[e] - mean) * rs * g[c] + bb[c];
    xo[base + c] = o;
    xbo[base + c] = (bf16)o;
  }
}

// ---------------- downsample: segment-mean pool + null token + LN ----------------
// Reference segmentation (seg = cumsum(bnd)-bnd, bnd at t%5==0):
//   seg 0 = {0}; seg s (1..39) = {5s-4 .. 5s}. Output row 0 = null token, row 1+s = seg s.
__global__ __launch_bounds__(256) void k_down(const float* __restrict__ x, const float* __restrict__ nullt,
                                              const float* __restrict__ g, const float* __restrict__ bb,
                                              float* __restrict__ xo, bf16* __restrict__ xbo) {
  const int row = blockIdx.x, tid = threadIdx.x;
  const long base = (long)row * ED;
  __shared__ float red[4];
  if (row >= TT2 * NB) {
#pragma unroll
    for (int e = 0; e < 3; ++e) { xo[base + tid + e * 256] = 0.0f; xbo[base + tid + e * 256] = (bf16)0.0f; }
    return;
  }
  const int s = row >> 5, b = row & 31;
  float v[3];
  if (s == 0) {
#pragma unroll
    for (int e = 0; e < 3; ++e) v[e] = nullt[tid + e * 256];
  } else {
    const int seg = s - 1;
    const int t0 = (seg == 0) ? 0 : (5 * seg - 4);
    const int cnt = (seg == 0) ? 1 : 5;
#pragma unroll
    for (int e = 0; e < 3; ++e) {
      float a = 0.0f;
      for (int tt = 0; tt < cnt; ++tt) a += x[((long)((t0 + tt) * NB + b)) * ED + tid + e * 256];
      v[e] = a / (float)cnt;
    }
  }
  const float mean = block_sum(v[0] + v[1] + v[2], red, tid) * (1.0f / ED);
  float sq = 0.0f;
#pragma unroll
  for (int e = 0; e < 3; ++e) { const float dd = v[e] - mean; sq += dd * dd; }
  const float var = block_sum(sq, red, tid) * (1.0f / ED);
  const float rs = rsqrtf(var + 1e-5f);
#pragma unroll
  for (int e = 0; e < 3; ++e) {
    const int c = tid + e * 256;
    const float o = (v[e] - mean) * rs * g[c] + bb[c];
    xo[base + c] = o;
    xbo[base + c] = (bf16)o;
  }
}

// ---------------- final token mean (fp32) ----------------
__global__ __launch_bounds__(256) void k_mean(const float* __restrict__ x2, float* __restrict__ xm) {
  const int b = blockIdx.x, tid = threadIdx.x;
#pragma unroll
  for (int e = 0; e < 3; ++e) {
    const int c = tid + e * 256;
    float a = 0.0f;
    for (int s = 0; s < TT2; ++s) a += x2[((long)(s * NB + b)) * ED + c];
    xm[(long)b * ED + c] = a * (1.0f / TT2);
  }
}

// ---------------- classifier head (fp32 dot, wave per (b,n)) ----------------
__global__ __launch_bounds__(256) void k_head(const float* __restrict__ xm, const float* __restrict__ hw,
                                              const float* __restrict__ hbias, float* __restrict__ out) {
  const int gid = blockIdx.x * 4 + (threadIdx.x >> 6);
  const int l = threadIdx.x & 63;
  if (gid >= NB * 1000) return;
  const int b = gid / 1000, n = gid % 1000;
  const float* xr = xm + (long)b * ED;
  const float* wr = hw + (long)n * ED;
  float a = 0.0f;
#pragma unroll
  for (int e = 0; e < 12; ++e) a += xr[l + 64 * e] * wr[l + 64 * e];
#pragma unroll
  for (int o = 32; o; o >>= 1) a += __shfl_xor(a, o);
  if (l == 0) out[(long)b * 1000 + n] = a + hbias[n];
}

// =======================================================================
extern "C" void kernel_launch(void* const* d_in, const int* in_sizes, int n_in,
                              void* d_out, int out_size, void* d_ws, size_t ws_size,
                              hipStream_t stream) {
  const float* in_x     = (const float*)d_in[0];
  const float* patch_w  = (const float*)d_in[1];
  const float* patch_b  = (const float*)d_in[2];
  const float* r_w_bias = (const float*)d_in[3];
  const float* r_r_bias = (const float*)d_in[4];
  const float* qkv_w    = (const float*)d_in[5];
  const float* qkv_b    = (const float*)d_in[6];
  const float* rnet_w   = (const float*)d_in[7];
  const float* rnet_b   = (const float*)d_in[8];
  const float* onet_w   = (const float*)d_in[9];
  const float* onet_b   = (const float*)d_in[10];
  const float* ln1_g    = (const float*)d_in[11];
  const float* ln1_b    = (const float*)d_in[12];
  const float* ff1_w    = (const float*)d_in[13];
  const float* ff1_b    = (const float*)d_in[14];
  const float* ff2_w    = (const float*)d_in[15];
  const float* ff2_b    = (const float*)d_in[16];
  const float* ln2_g    = (const float*)d_in[17];
  const float* ln2_b    = (const float*)d_in[18];
  const float* null_tok = (const float*)d_in[19];
  const float* down_g   = (const float*)d_in[20];
  const float* down_b   = (const float*)d_in[21];
  const float* head_w   = (const float*)d_in[22];
  const float* head_b   = (const float*)d_in[23];
  float* out = (float*)d_out;

  // ---- workspace layout: lifetime-unioned arenas, ~189 MB total ----
  char* base = (char*)d_ws;
  size_t off = 0;
  auto take = [&](size_t bytes) -> char* {
    char* r = base + off;
    off += (bytes + 255) & ~(size_t)255;
    return r;
  };

  // persistent
  float* x    = (float*)take((size_t)MM1 * ED * 4);
  bf16*  xb   = (bf16*)take((size_t)MM1 * ED * 2);
  float* x2   = (float*)take((size_t)MM2 * ED * 4);
  bf16*  xb2  = (bf16*)take((size_t)MM2 * ED * 2);
  bf16*  rkb  = (bf16*)take((size_t)LTOT * NH * TPM * 64 * 2);
  bf16*  rbf  = (bf16*)take((size_t)256 * ED * 2);
  bf16*  r2bf = (bf16*)take((size_t)128 * ED * 2);
  float* xm   = (float*)take((size_t)NB * ED * 4);

  // Arena W: per-layer weights; setup overlay = wrnet(11.8M)+wpatch(1.2M)
  char* arenaW = take((size_t)(2304 * 768 + 768 * 768 + 3072 * 768 + 768 * 3072) * 2);
  bf16* wq = (bf16*)arenaW;
  bf16* wo = wq + (size_t)2304 * 768;
  bf16* w1 = wo + (size_t)768 * 768;
  bf16* w2 = w1 + (size_t)3072 * 768;
  bf16* wrnet  = (bf16*)arenaW;                       // setup only
  bf16* wpatch = wrnet + (size_t)LTOT * 768 * 768;    // setup only

  // Arena Q: attention operand tiles; setup overlay = A0 (im2col, 9.6M)
  char* arenaQ = take((size_t)(3 * TPM * 64 + 64 * KPM) * BHN * 2);
  bf16* qw  = (bf16*)arenaQ;
  bf16* qr  = qw + (size_t)BHN * TPM * 64;
  bf16* kkb = qr + (size_t)BHN * TPM * 64;
  bf16* vT  = kkb + (size_t)BHN * TPM * 64;
  bf16* A0  = (bf16*)arenaQ;                          // setup only

  // Arena H: heads(bf16, 28.9M) then prob(35.8M); setup overlay = rkall1+rkall2
  char* arenaH = take((size_t)BHN * TPM * KPM * 2);
  bf16*  headsb = (bf16*)arenaH;
  bf16*  prob   = (bf16*)arenaH;
  float* rkall1 = (float*)arenaH;                     // setup only (1.6M)
  float* rkall2 = (float*)(arenaH + (size_t)256 * 1536 * 4);  // setup only (3.1M)

  // Arena S: scores S (fp32, 66.5M) then {avb, gout, hb} (67.4M)
  char* arenaS = take((size_t)MM1 * ED * 2 + (size_t)MM1 * ED * 4 + (size_t)MM1 * FFD * 2);
  float* S    = (float*)arenaS;
  bf16*  avb  = (bf16*)arenaS;
  float* gout = (float*)(arenaS + (size_t)MM1 * ED * 2);
  bf16*  hb   = (bf16*)(arenaS + (size_t)MM1 * ED * 2 + (size_t)MM1 * ED * 4);

  if (off > ws_size) return;  // diagnostic: ws too small -> clean absmax fail, not a fault

  // ---- setup: pos embeddings, weight conversions, patch embed, rk ----
  k_posemb<<<dim3(256), dim3(768), 0, stream>>>(rbf, TT1);
  k_posemb<<<dim3(128), dim3(768), 0, stream>>>(r2bf, TT2);
  k_cvt<<<dim3(1024), dim3(256), 0, stream>>>(rnet_w, wrnet, (long)LTOT * 768 * 768 / 8);
  k_cvt<<<dim3(288), dim3(256), 0, stream>>>(patch_w, wpatch, (long)768 * 768 / 8);
  k_im2col<<<dim3((MM1 * ED + 255) / 256), dim3(256), 0, stream>>>(in_x, A0);
  k_gemm<2><<<dim3(6, 49), dim3(256), 0, stream>>>(A0, wpatch, patch_b, x, xb, MM1, ED, ED);
  k_gemm<0><<<dim3(12, 2), dim3(256), 0, stream>>>(rbf, wrnet, rnet_b, rkall1, nullptr, 256, 1536, ED);
  k_gemm<0><<<dim3(48, 1), dim3(256), 0, stream>>>(r2bf, wrnet + (size_t)2 * 768 * 768, rnet_b + 2 * 768,
                                                   rkall2, nullptr, 128, 6144, ED);
  k_rkrepack<<<dim3(TPM, 2), dim3(768), 0, stream>>>(rkall1, rkb, TT1, 1536, 0);
  k_rkrepack<<<dim3(48, 8), dim3(768), 0, stream>>>(rkall2, rkb, TT2, 6144, 2);

  // ---- transformer layers ----
  for (int l = 0; l < LTOT; ++l) {
    const bool pre = (l < 2);
    const int T = pre ? TT1 : TT2;
    const int TPu = pre ? TPM : 48;   // padded token count in use
    const int KPV = pre ? KPM : 64;   // padded PV K dim in use
    const int Mp = pre ? MM1 : MM2;
    const int Mreal = pre ? MM1 : M2R;
    float* xcur = pre ? x : x2;
    bf16* xbcur = pre ? xb : xb2;

    k_cvt4<<<dim3(1024), dim3(256), 0, stream>>>(
        qkv_w + (size_t)l * 2304 * 768, onet_w + (size_t)l * 768 * 768,
        ff1_w + (size_t)l * 3072 * 768, ff2_w + (size_t)l * 768 * 3072,
        wq, wo, w1, w2, 2304 * 768 / 8, 768 * 768 / 8, 3072 * 768 / 8, 768 * 3072 / 8);

    k_gemm<3><<<dim3(18, Mp / 128), dim3(256), 0, stream>>>(xbcur, wq, qkv_b + (size_t)l * 2304,
                                                            nullptr, headsb, Mp, 3 * ED, ED);
    k_repack<<<dim3(TPu, BHN), dim3(64), 0, stream>>>(headsb, r_w_bias, r_r_bias, qw, qr, kkb, vT, T);
    k_scoreAC<<<dim3(TPu / 16, TPu / 16, BHN), dim3(64), 0, stream>>>(qw, kkb, S);
    k_scoreBD<<<dim3(TPu / 16, TPu / 16, BHN), dim3(64), 0, stream>>>(
        qr, rkb + (size_t)l * NH * TPM * 64, S, T);
    k_softmax<<<dim3(TPu, BHN), dim3(256), 0, stream>>>(S, prob, T, KPV);
    k_pv<<<dim3(TPu / 16, 4, BHN), dim3(64), 0, stream>>>(prob, vT, avb, T, KPV);
    k_gemm<0><<<dim3(6, Mp / 128), dim3(256), 0, stream>>>(avb, wo, onet_b + (size_t)l * 768,
                                                           gout, nullptr, Mp, ED, ED);
    k_ln<<<dim3(Mp), dim3(256), 0, stream>>>(xcur, gout, ln1_g + (size_t)l * 768, ln1_b + (size_t)l * 768,
                                             xcur, xbcur, Mreal);
    k_gemm<1><<<dim3(24, Mp / 128), dim3(256), 0, stream>>>(xbcur, w1, ff1_b + (size_t)l * 3072,
                                                            nullptr, hb, Mp, FFD, ED);
    k_gemm<0><<<dim3(6, Mp / 128), dim3(256), 0, stream>>>(hb, w2, ff2_b + (size_t)l * 768,
                                                           gout, nullptr, Mp, ED, FFD);
    k_ln<<<dim3(Mp), dim3(256), 0, stream>>>(xcur, gout, ln2_g + (size_t)l * 768, ln2_b + (size_t)l * 768,
                                             xcur, xbcur, Mreal);

    if (l == 1) {  // pool 196 -> {null} + 40 segments, LN -> short-stack input
      k_down<<<dim3(MM2), dim3(256), 0, stream>>>(x, null_tok, down_g, down_b, x2, xb2);
    }
  }

  // ---- final: token mean + classifier head (fp32) ----
  k_mean<<<dim3(NB), dim3(256), 0, stream>>>(x2, xm);
  k_head<<<dim3(8000), dim3(256), 0, stream>>>(xm, head_w, head_b, out);
}

// Round 4
// 2099.766 us; speedup vs baseline: 1.2750x; 1.2281x over previous
//
#include <hip/hip_runtime.h>
#include <hip/hip_bf16.h>
#include <math.h>
#include <stdint.h>

// ---------------- types ----------------
typedef __bf16 bf16;
typedef __bf16 bf16x8 __attribute__((ext_vector_type(8)));
typedef float  f32x4  __attribute__((ext_vector_type(4)));

// ---------------- model constants ----------------
#define NB   32        // batch
#define ED   768       // embed dim
#define NH   12        // heads
#define DHD  64        // head dim
#define FFD  3072
#define TT1  196       // pre-stack tokens
#define TT2  41        // short-stack tokens
#define TPM  208       // padded token dim (row stride for q/k/rk/S/prob)
#define KPM  224       // padded K dim for PV (col stride for prob/vT)
#define MM1  6272      // 196*32  (= 49*128)
#define MM2  1408      // padded 41*32=1312 -> 11*128
#define M2R  1312
#define BHN  384       // 32*12
#define LTOT 10
#define SCL  0.125f    // 1/sqrt(64)

// ---------------- async global->LDS (16B per lane, wave-uniform LDS base) ----------------
__device__ __forceinline__ void gload_lds16(const bf16* g, bf16* l) {
  __builtin_amdgcn_global_load_lds(
      (__attribute__((address_space(1))) void*)(uintptr_t)g,
      (__attribute__((address_space(3))) void*)(uint32_t)(uintptr_t)l,
      16, 0, 0);
}

// ---------------- helpers ----------------
__device__ __forceinline__ float block_sum(float v, float* red, int tid) {
#pragma unroll
  for (int o = 32; o; o >>= 1) v += __shfl_xor(v, o);
  if ((tid & 63) == 0) red[tid >> 6] = v;
  __syncthreads();
  float t = red[0] + red[1] + red[2] + red[3];
  __syncthreads();
  return t;
}

__device__ __forceinline__ bf16x8 cvt8(const float* __restrict__ s) {
  const f32x4 a = *(const f32x4*)s;
  const f32x4 b = *(const f32x4*)(s + 4);
  bf16x8 o;
#pragma unroll
  for (int j = 0; j < 4; ++j) { o[j] = (bf16)a[j]; o[4 + j] = (bf16)b[j]; }
  return o;
}

// ---------------- fp32 -> bf16 converters (vectorized, n % 8 == 0) ----------------
__global__ void k_cvt(const float* __restrict__ s, bf16* __restrict__ d, long n8) {
  for (long i = (long)blockIdx.x * 256 + threadIdx.x; i < n8; i += (long)gridDim.x * 256)
    *(bf16x8*)&d[i * 8] = cvt8(&s[i * 8]);
}

__global__ void k_cvt4(const float* __restrict__ a, const float* __restrict__ b,
                       const float* __restrict__ c, const float* __restrict__ d,
                       bf16* __restrict__ oa, bf16* __restrict__ ob,
                       bf16* __restrict__ oc, bf16* __restrict__ od,
                       int na8, int nb8, int nc8, int nd8) {
  const long tot = (long)na8 + nb8 + nc8 + nd8;
  for (long i = (long)blockIdx.x * 256 + threadIdx.x; i < tot; i += (long)gridDim.x * 256) {
    if (i < na8) *(bf16x8*)&oa[i * 8] = cvt8(&a[i * 8]);
    else if (i < (long)na8 + nb8) { const long j = i - na8; *(bf16x8*)&ob[j * 8] = cvt8(&b[j * 8]); }
    else if (i < (long)na8 + nb8 + nc8) { const long j = i - na8 - nb8; *(bf16x8*)&oc[j * 8] = cvt8(&c[j * 8]); }
    else { const long j = i - na8 - nb8 - nc8; *(bf16x8*)&od[j * 8] = cvt8(&d[j * 8]); }
  }
}

// ---------------- sinusoidal pos emb (descending pos), bf16 out ----------------
__global__ void k_posemb(bf16* __restrict__ out, int T) {
  const int t = blockIdx.x, c = threadIdx.x;   // block = 768
  float v = 0.0f;
  if (t < T) {
    const float pos = (float)(T - 1 - t);
    const int ci = (c < 384) ? c : c - 384;
    const float invf = expf(-(float)ci * (9.210340371976184f / 384.0f)); // ln(10000)
    const float a = pos * invf;
    v = (c < 384) ? sinf(a) : cosf(a);
  }
  out[(long)t * ED + c] = (bf16)v;
}

// ---------------- im2col for patch embed: A0[t*32+b][c*256+i*16+j] ----------------
__global__ void k_im2col(const float* __restrict__ x, bf16* __restrict__ A0) {
  const long idx = (long)blockIdx.x * 256 + threadIdx.x;
  if (idx >= (long)MM1 * ED) return;
  const int row = (int)(idx / ED), k = (int)(idx % ED);
  const int t = row >> 5, b = row & 31;
  const int c = k >> 8, rem = k & 255, i = rem >> 4, j = rem & 15;
  const int py = t / 14, px = t % 14;
  A0[idx] = (bf16)x[((long)(b * 3 + c) * 224 + (py * 16 + i)) * 224 + px * 16 + j];
}

// ---------------- GEMM: C[m,n] = sum_k A[m,k]*B[n,k] + bias[n] ----------------
// 128x128 tile, BK=64, 4 waves. 2-phase double-buffered K-loop (T3-minimum):
// next tile's global_load_lds issued BEFORE current tile's ds_read+MFMA;
// one vmcnt(0)+s_barrier per K-step. LDS tiles XOR-swizzled at 16B-unit
// granularity (unit ^= row&7) to kill the 16-way stride-128B read conflict;
// global_load_lds writes linearly, so the SOURCE unit is inverse-swizzled
// (rule 21: both-sides-or-neither).
// EPI: 0=fp32; 1=GELU->bf16; 2=fp32+bf16; 3=bf16. M%128==0, N%128==0, K%64==0.
template <int EPI>
__global__ __launch_bounds__(256) void k_gemm(const bf16* __restrict__ A, const bf16* __restrict__ Bw,
                                              const float* __restrict__ bias,
                                              float* __restrict__ Cf, bf16* __restrict__ Cb,
                                              int M, int N, int K) {
  __shared__ __align__(16) bf16 As[2][128 * 64];
  __shared__ __align__(16) bf16 Bs[2][128 * 64];
  const int tid = threadIdx.x;
  const int l = tid & 63, w = tid >> 6;
  const int wr = w >> 1, wc = w & 1;
  const int m0 = blockIdx.y * 128, n0 = blockIdx.x * 128;
  // staging geometry: lane l covers row rbase+(l>>3), 16B-unit (l&7) of LDS;
  // source unit inverse-swizzled: (l&7) ^ (l>>3)  (row&7 == l>>3 since rbase%8==0)
  const int srow = l >> 3;
  const int scol = ((l & 7) ^ (l >> 3)) * 8;
  f32x4 acc[4][4] = {};

  const int nt = K >> 6;
  // prologue: stage tile 0
#pragma unroll
  for (int p = 0; p < 4; ++p) {
    const int rbase = w * 32 + p * 8;
    gload_lds16(&A[(long)(m0 + rbase + srow) * K + scol], &As[0][rbase * 64]);
    gload_lds16(&Bw[(long)(n0 + rbase + srow) * K + scol], &Bs[0][rbase * 64]);
  }
  asm volatile("s_waitcnt vmcnt(0)" ::: "memory");
  __builtin_amdgcn_s_barrier();

  int cur = 0;
  for (int t = 0; t < nt; ++t) {
    if (t + 1 < nt) {  // issue next tile's loads; they stay in flight under the MFMAs
      const int k1 = (t + 1) << 6;
#pragma unroll
      for (int p = 0; p < 4; ++p) {
        const int rbase = w * 32 + p * 8;
        gload_lds16(&A[(long)(m0 + rbase + srow) * K + k1 + scol], &As[cur ^ 1][rbase * 64]);
        gload_lds16(&Bw[(long)(n0 + rbase + srow) * K + k1 + scol], &Bs[cur ^ 1][rbase * 64]);
      }
    }
#pragma unroll
    for (int kk = 0; kk < 64; kk += 32) {
      bf16x8 af[4], bg[4];
      const int ub = (kk >> 3) + (l >> 4);   // 16B-unit base within row
#pragma unroll
      for (int m = 0; m < 4; ++m) {
        const int row = wr * 64 + m * 16 + (l & 15);
        af[m] = *(const bf16x8*)&As[cur][row * 64 + (ub ^ (row & 7)) * 8];
      }
#pragma unroll
      for (int n = 0; n < 4; ++n) {
        const int row = wc * 64 + n * 16 + (l & 15);
        bg[n] = *(const bf16x8*)&Bs[cur][row * 64 + (ub ^ (row & 7)) * 8];
      }
#pragma unroll
      for (int m = 0; m < 4; ++m)
#pragma unroll
        for (int n = 0; n < 4; ++n)
          acc[m][n] = __builtin_amdgcn_mfma_f32_16x16x32_bf16(af[m], bg[n], acc[m][n], 0, 0, 0);
    }
    asm volatile("s_waitcnt vmcnt(0)" ::: "memory");  // next tile's LDS writes landed
    __builtin_amdgcn_s_barrier();                      // + everyone done reading cur
    cur ^= 1;
  }

#pragma unroll
  for (int m = 0; m < 4; ++m) {
    const int row = m0 + wr * 64 + m * 16 + 4 * (l >> 4);
#pragma unroll
    for (int n = 0; n < 4; ++n) {
      const int col = n0 + wc * 64 + n * 16 + (l & 15);
      const float bv = bias[col];
#pragma unroll
      for (int r = 0; r < 4; ++r) {
        const float v = acc[m][n][r] + bv;
        const long off = (long)(row + r) * N + col;
        if (EPI == 0) {
          Cf[off] = v;
        } else if (EPI == 1) {
          Cb[off] = (bf16)(0.5f * v * (1.0f + erff(v * 0.70710678118654752f)));
        } else if (EPI == 2) {
          Cf[off] = v;
          Cb[off] = (bf16)v;
        } else {
          Cb[off] = (bf16)v;
        }
      }
    }
  }
}

// ---------------- repack qkv heads -> attention layouts ----------------
// qw/qr/kk: [bh][TPM][64] bf16 (rows >= T zeroed). vT: [bh][64][KPM] bf16.
__global__ void k_repack(const bf16* __restrict__ heads, const float* __restrict__ rwb,
                         const float* __restrict__ rrb,
                         bf16* __restrict__ qw, bf16* __restrict__ qr,
                         bf16* __restrict__ kkb, bf16* __restrict__ vT, int T) {
  const int i = blockIdx.x, bh = blockIdx.y, d = threadIdx.x;  // block = 64
  const int b = bh / NH, n = bh % NH;
  const long qoff = (long)bh * TPM * 64 + (long)i * 64 + d;
  const long voff = (long)bh * 64 * KPM + (long)d * KPM + i;
  if (i < T) {
    const long src = ((long)(i * NB + b)) * (3 * ED) + n * 64 + d;
    const float q = (float)heads[src];
    qw[qoff] = (bf16)(q + rwb[n * 64 + d]);
    qr[qoff] = (bf16)(q + rrb[n * 64 + d]);
    kkb[qoff] = heads[src + ED];
    vT[voff] = heads[src + 2 * ED];
  } else {
    qw[qoff] = (bf16)0.0f; qr[qoff] = (bf16)0.0f;
    kkb[qoff] = (bf16)0.0f; vT[voff] = (bf16)0.0f;
  }
}

// ---------------- rk repack: rkall fp32 [rows][nl*768] -> rkb bf16 [l][n][TPM][64] ----------------
__global__ void k_rkrepack(const float* __restrict__ rkall, bf16* __restrict__ rkb,
                           int T, int Ncols, int l0) {
  const int i = blockIdx.x, z = blockIdx.y, d = threadIdx.x;  // block = 768
  const float v = (i < T) ? rkall[(long)i * Ncols + z * ED + d] : 0.0f;
  const int n = d >> 6, dh = d & 63;
  rkb[(((long)(l0 + z) * NH + n) * TPM + i) * 64 + dh] = (bf16)v;
}

// ---------------- AC scores: S[i][j] = SCL * (q+rwb)_i . k_j ----------------
__global__ __launch_bounds__(64) void k_scoreAC(const bf16* __restrict__ qw,
                                                const bf16* __restrict__ kkb,
                                                float* __restrict__ S) {
  const int ti = blockIdx.x, tj = blockIdx.y, bh = blockIdx.z;
  const int l = threadIdx.x;
  const bf16* Ap = qw + (long)bh * TPM * 64 + (ti * 16 + (l & 15)) * 64 + 8 * (l >> 4);
  const bf16* Bp = kkb + (long)bh * TPM * 64 + (tj * 16 + (l & 15)) * 64 + 8 * (l >> 4);
  f32x4 c = {};
  c = __builtin_amdgcn_mfma_f32_16x16x32_bf16(*(const bf16x8*)Ap, *(const bf16x8*)Bp, c, 0, 0, 0);
  c = __builtin_amdgcn_mfma_f32_16x16x32_bf16(*(const bf16x8*)(Ap + 32), *(const bf16x8*)(Bp + 32), c, 0, 0, 0);
  float* outp = S + (long)bh * TPM * TPM;
  const int col = tj * 16 + (l & 15);
  const int rb = ti * 16 + 4 * (l >> 4);
#pragma unroll
  for (int r = 0; r < 4; ++r) outp[(long)(rb + r) * TPM + col] = SCL * c[r];
}

// ---------------- BD scores with rel_shift applied at write (scatter-add) ----------------
// BDraw[a][b] lands at m = a*(T+1)+b+1; if m>=T: i=m/T-1, j=m-(i+1)*T; S[i][j] += SCL*val.
// Bijective onto {j != i+1}; diagonal j=i+1 keeps bd=0 (matches reference zero-pad).
__global__ __launch_bounds__(64) void k_scoreBD(const bf16* __restrict__ qr,
                                                const bf16* __restrict__ rkb_l,
                                                float* __restrict__ S, int T) {
  const int ti = blockIdx.x, tj = blockIdx.y, bh = blockIdx.z;
  const int l = threadIdx.x;
  const bf16* Ap = qr + (long)bh * TPM * 64 + (ti * 16 + (l & 15)) * 64 + 8 * (l >> 4);
  const bf16* Bp = rkb_l + (long)(bh % NH) * TPM * 64 + (tj * 16 + (l & 15)) * 64 + 8 * (l >> 4);
  f32x4 c = {};
  c = __builtin_amdgcn_mfma_f32_16x16x32_bf16(*(const bf16x8*)Ap, *(const bf16x8*)Bp, c, 0, 0, 0);
  c = __builtin_amdgcn_mfma_f32_16x16x32_bf16(*(const bf16x8*)(Ap + 32), *(const bf16x8*)(Bp + 32), c, 0, 0, 0);
  float* Sb = S + (long)bh * TPM * TPM;
  const int b = tj * 16 + (l & 15);
  const int ab = ti * 16 + 4 * (l >> 4);
#pragma unroll
  for (int r = 0; r < 4; ++r) {
    const int a = ab + r;
    if (a < T && b < T) {
      const int m = a * (T + 1) + b + 1;
      if (m >= T) {
        const int i = m / T - 1;
        const int j = m - (i + 1) * T;
        Sb[(long)i * TPM + j] += SCL * c[r];
      }
    }
  }
}

// ---------------- softmax over fused scores ----------------
__global__ __launch_bounds__(256) void k_softmax(const float* __restrict__ S,
                                                 bf16* __restrict__ prob, int T, int KPV) {
  const int i = blockIdx.x, bh = blockIdx.y, tid = threadIdx.x;
  bf16* prow = prob + (long)bh * TPM * KPM + (long)i * KPM;
  if (i >= T) {  // clean padded rows (uniform per block)
    for (int c = tid; c < KPV; c += 256) prow[c] = (bf16)0.0f;
    return;
  }
  const float* srow = S + (long)bh * TPM * TPM + (long)i * TPM;
  float val = -3.0e38f;
  if (tid < T) val = srow[tid];
  __shared__ float red[8];
  float mx = val;
#pragma unroll
  for (int o = 32; o; o >>= 1) mx = fmaxf(mx, __shfl_xor(mx, o));
  if ((tid & 63) == 0) red[tid >> 6] = mx;
  __syncthreads();
  mx = fmaxf(fmaxf(red[0], red[1]), fmaxf(red[2], red[3]));
  const float e = (tid < T) ? expf(val - mx) : 0.0f;
  float sm = e;
#pragma unroll
  for (int o = 32; o; o >>= 1) sm += __shfl_xor(sm, o);
  if ((tid & 63) == 0) red[4 + (tid >> 6)] = sm;
  __syncthreads();
  sm = red[4] + red[5] + red[6] + red[7];
  if (tid < KPV) prow[tid] = (tid < T) ? (bf16)(e / sm) : (bf16)0.0f;
}

// ---------------- PV: av[i,d] = sum_j prob[i,j] * v[j,d] ----------------
__global__ __launch_bounds__(64) void k_pv(const bf16* __restrict__ prob, const bf16* __restrict__ vT,
                                           bf16* __restrict__ avb, int T, int KPV) {
  const int ti = blockIdx.x, dj = blockIdx.y, bh = blockIdx.z;
  const int l = threadIdx.x;
  const int b = bh / NH, n = bh % NH;
  const bf16* Ap = prob + (long)bh * TPM * KPM + (ti * 16 + (l & 15)) * KPM + 8 * (l >> 4);
  const bf16* Bp = vT + (long)bh * 64 * KPM + (dj * 16 + (l & 15)) * KPM + 8 * (l >> 4);
  f32x4 c = {};
  for (int s = 0; s < KPV; s += 32)
    c = __builtin_amdgcn_mfma_f32_16x16x32_bf16(*(const bf16x8*)(Ap + s), *(const bf16x8*)(Bp + s), c, 0, 0, 0);
  const int d = dj * 16 + (l & 15);
  const int ib = ti * 16 + 4 * (l >> 4);
#pragma unroll
  for (int r = 0; r < 4; ++r) {
    const int i = ib + r;
    if (i < T) avb[((long)(i * NB + b)) * ED + n * 64 + d] = (bf16)c[r];
  }
}

// ---------------- residual + LayerNorm (fp32 master, bf16 copy) ----------------
__global__ __launch_bounds__(256) void k_ln(const float* __restrict__ xin, const float* __restrict__ add,
                                            const float* __restrict__ g, const float* __restrict__ bb,
                                            float* __restrict__ xo, bf16* __restrict__ xbo, int Mreal) {
  const int row = blockIdx.x, tid = threadIdx.x;
  const long base = (long)row * ED;
  __shared__ float red[4];
  if (row >= Mreal) {
#pragma unroll
    for (int e = 0; e < 3; ++e) { xo[base + tid + e * 256] = 0.0f; xbo[base + tid + e * 256] = (bf16)0.0f; }
    return;
  }
  float v[3];
#pragma unroll
  for (int e = 0; e < 3; ++e) v[e] = xin[base + tid + e * 256] + add[base + tid + e * 256];
  const float mean = block_sum(v[0] + v[1] + v[2], red, tid) * (1.0f / ED);
  float sq = 0.0f;
#pragma unroll
  for (int e = 0; e < 3; ++e) { const float dd = v[e] - mean; sq += dd * dd; }
  const float var = block_sum(sq, red, tid) * (1.0f / ED);
  const float rs = rsqrtf(var + 1e-5f);
#pragma unroll
  for (int e = 0; e < 3; ++e) {
    const int c = tid + e * 256;
    const float o = (v[e] - mean) * rs * g[c] + bb[c];
    xo[base + c] = o;
    xbo[base + c] = (bf16)o;
  }
}

// ---------------- downsample: segment-mean pool + null token + LN ----------------
// Reference segmentation (seg = cumsum(bnd)-bnd, bnd at t%5==0):
//   seg 0 = {0}; seg s (1..39) = {5s-4 .. 5s}. Output row 0 = null token, row 1+s = seg s.
__global__ __launch_bounds__(256) void k_down(const float* __restrict__ x, const float* __restrict__ nullt,
                                              const float* __restrict__ g, const float* __restrict__ bb,
                                              float* __restrict__ xo, bf16* __restrict__ xbo) {
  const int row = blockIdx.x, tid = threadIdx.x;
  const long base = (long)row * ED;
  __shared__ float red[4];
  if (row >= TT2 * NB) {
#pragma unroll
    for (int e = 0; e < 3; ++e) { xo[base + tid + e * 256] = 0.0f; xbo[base + tid + e * 256] = (bf16)0.0f; }
    return;
  }
  const int s = row >> 5, b = row & 31;
  float v[3];
  if (s == 0) {
#pragma unroll
    for (int e = 0; e < 3; ++e) v[e] = nullt[tid + e * 256];
  } else {
    const int seg = s - 1;
    const int t0 = (seg == 0) ? 0 : (5 * seg - 4);
    const int cnt = (seg == 0) ? 1 : 5;
#pragma unroll
    for (int e = 0; e < 3; ++e) {
      float a = 0.0f;
      for (int tt = 0; tt < cnt; ++tt) a += x[((long)((t0 + tt) * NB + b)) * ED + tid + e * 256];
      v[e] = a / (float)cnt;
    }
  }
  const float mean = block_sum(v[0] + v[1] + v[2], red, tid) * (1.0f / ED);
  float sq = 0.0f;
#pragma unroll
  for (int e = 0; e < 3; ++e) { const float dd = v[e] - mean; sq += dd * dd; }
  const float var = block_sum(sq, red, tid) * (1.0f / ED);
  const float rs = rsqrtf(var + 1e-5f);
#pragma unroll
  for (int e = 0; e < 3; ++e) {
    const int c = tid + e * 256;
    const float o = (v[e] - mean) * rs * g[c] + bb[c];
    xo[base + c] = o;
    xbo[base + c] = (bf16)o;
  }
}

// ---------------- final token mean (fp32) ----------------
__global__ __launch_bounds__(256) void k_mean(const float* __restrict__ x2, float* __restrict__ xm) {
  const int b = blockIdx.x, tid = threadIdx.x;
#pragma unroll
  for (int e = 0; e < 3; ++e) {
    const int c = tid + e * 256;
    float a = 0.0f;
    for (int s = 0; s < TT2; ++s) a += x2[((long)(s * NB + b)) * ED + c];
    xm[(long)b * ED + c] = a * (1.0f / TT2);
  }
}

// ---------------- classifier head (fp32 dot, wave per (b,n)) ----------------
__global__ __launch_bounds__(256) void k_head(const float* __restrict__ xm, const float* __restrict__ hw,
                                              const float* __restrict__ hbias, float* __restrict__ out) {
  const int gid = blockIdx.x * 4 + (threadIdx.x >> 6);
  const int l = threadIdx.x & 63;
  if (gid >= NB * 1000) return;
  const int b = gid / 1000, n = gid % 1000;
  const float* xr = xm + (long)b * ED;
  const float* wr = hw + (long)n * ED;
  float a = 0.0f;
#pragma unroll
  for (int e = 0; e < 12; ++e) a += xr[l + 64 * e] * wr[l + 64 * e];
#pragma unroll
  for (int o = 32; o; o >>= 1) a += __shfl_xor(a, o);
  if (l == 0) out[(long)b * 1000 + n] = a + hbias[n];
}

// =======================================================================
extern "C" void kernel_launch(void* const* d_in, const int* in_sizes, int n_in,
                              void* d_out, int out_size, void* d_ws, size_t ws_size,
                              hipStream_t stream) {
  const float* in_x     = (const float*)d_in[0];
  const float* patch_w  = (const float*)d_in[1];
  const float* patch_b  = (const float*)d_in[2];
  const float* r_w_bias = (const float*)d_in[3];
  const float* r_r_bias = (const float*)d_in[4];
  const float* qkv_w    = (const float*)d_in[5];
  const float* qkv_b    = (const float*)d_in[6];
  const float* rnet_w   = (const float*)d_in[7];
  const float* rnet_b   = (const float*)d_in[8];
  const float* onet_w   = (const float*)d_in[9];
  const float* onet_b   = (const float*)d_in[10];
  const float* ln1_g    = (const float*)d_in[11];
  const float* ln1_b    = (const float*)d_in[12];
  const float* ff1_w    = (const float*)d_in[13];
  const float* ff1_b    = (const float*)d_in[14];
  const float* ff2_w    = (const float*)d_in[15];
  const float* ff2_b    = (const float*)d_in[16];
  const float* ln2_g    = (const float*)d_in[17];
  const float* ln2_b    = (const float*)d_in[18];
  const float* null_tok = (const float*)d_in[19];
  const float* down_g   = (const float*)d_in[20];
  const float* down_b   = (const float*)d_in[21];
  const float* head_w   = (const float*)d_in[22];
  const float* head_b   = (const float*)d_in[23];
  float* out = (float*)d_out;

  // ---- workspace layout: lifetime-unioned arenas, ~189 MB total ----
  char* base = (char*)d_ws;
  size_t off = 0;
  auto take = [&](size_t bytes) -> char* {
    char* r = base + off;
    off += (bytes + 255) & ~(size_t)255;
    return r;
  };

  // persistent
  float* x    = (float*)take((size_t)MM1 * ED * 4);
  bf16*  xb   = (bf16*)take((size_t)MM1 * ED * 2);
  float* x2   = (float*)take((size_t)MM2 * ED * 4);
  bf16*  xb2  = (bf16*)take((size_t)MM2 * ED * 2);
  bf16*  rkb  = (bf16*)take((size_t)LTOT * NH * TPM * 64 * 2);
  bf16*  rbf  = (bf16*)take((size_t)256 * ED * 2);
  bf16*  r2bf = (bf16*)take((size_t)128 * ED * 2);
  float* xm   = (float*)take((size_t)NB * ED * 4);

  // Arena W: per-layer weights; setup overlay = wrnet(11.8M)+wpatch(1.2M)
  char* arenaW = take((size_t)(2304 * 768 + 768 * 768 + 3072 * 768 + 768 * 3072) * 2);
  bf16* wq = (bf16*)arenaW;
  bf16* wo = wq + (size_t)2304 * 768;
  bf16* w1 = wo + (size_t)768 * 768;
  bf16* w2 = w1 + (size_t)3072 * 768;
  bf16* wrnet  = (bf16*)arenaW;                       // setup only
  bf16* wpatch = wrnet + (size_t)LTOT * 768 * 768;    // setup only

  // Arena Q: attention operand tiles; setup overlay = A0 (im2col, 9.6M)
  char* arenaQ = take((size_t)(3 * TPM * 64 + 64 * KPM) * BHN * 2);
  bf16* qw  = (bf16*)arenaQ;
  bf16* qr  = qw + (size_t)BHN * TPM * 64;
  bf16* kkb = qr + (size_t)BHN * TPM * 64;
  bf16* vT  = kkb + (size_t)BHN * TPM * 64;
  bf16* A0  = (bf16*)arenaQ;                          // setup only

  // Arena H: heads(bf16, 28.9M) then prob(35.8M); setup overlay = rkall1+rkall2
  char* arenaH = take((size_t)BHN * TPM * KPM * 2);
  bf16*  headsb = (bf16*)arenaH;
  bf16*  prob   = (bf16*)arenaH;
  float* rkall1 = (float*)arenaH;                     // setup only (1.6M)
  float* rkall2 = (float*)(arenaH + (size_t)256 * 1536 * 4);  // setup only (3.1M)

  // Arena S: scores S (fp32, 66.5M) then {avb, gout, hb} (67.4M)
  char* arenaS = take((size_t)MM1 * ED * 2 + (size_t)MM1 * ED * 4 + (size_t)MM1 * FFD * 2);
  float* S    = (float*)arenaS;
  bf16*  avb  = (bf16*)arenaS;
  float* gout = (float*)(arenaS + (size_t)MM1 * ED * 2);
  bf16*  hb   = (bf16*)(arenaS + (size_t)MM1 * ED * 2 + (size_t)MM1 * ED * 4);

  if (off > ws_size) return;  // diagnostic: ws too small -> clean absmax fail, not a fault

  // ---- setup: pos embeddings, weight conversions, patch embed, rk ----
  k_posemb<<<dim3(256), dim3(768), 0, stream>>>(rbf, TT1);
  k_posemb<<<dim3(128), dim3(768), 0, stream>>>(r2bf, TT2);
  k_cvt<<<dim3(1024), dim3(256), 0, stream>>>(rnet_w, wrnet, (long)LTOT * 768 * 768 / 8);
  k_cvt<<<dim3(288), dim3(256), 0, stream>>>(patch_w, wpatch, (long)768 * 768 / 8);
  k_im2col<<<dim3((MM1 * ED + 255) / 256), dim3(256), 0, stream>>>(in_x, A0);
  k_gemm<2><<<dim3(6, 49), dim3(256), 0, stream>>>(A0, wpatch, patch_b, x, xb, MM1, ED, ED);
  k_gemm<0><<<dim3(12, 2), dim3(256), 0, stream>>>(rbf, wrnet, rnet_b, rkall1, nullptr, 256, 1536, ED);
  k_gemm<0><<<dim3(48, 1), dim3(256), 0, stream>>>(r2bf, wrnet + (size_t)2 * 768 * 768, rnet_b + 2 * 768,
                                                   rkall2, nullptr, 128, 6144, ED);
  k_rkrepack<<<dim3(TPM, 2), dim3(768), 0, stream>>>(rkall1, rkb, TT1, 1536, 0);
  k_rkrepack<<<dim3(48, 8), dim3(768), 0, stream>>>(rkall2, rkb, TT2, 6144, 2);

  // ---- transformer layers ----
  for (int l = 0; l < LTOT; ++l) {
    const bool pre = (l < 2);
    const int T = pre ? TT1 : TT2;
    const int TPu = pre ? TPM : 48;   // padded token count in use
    const int KPV = pre ? KPM : 64;   // padded PV K dim in use
    const int Mp = pre ? MM1 : MM2;
    const int Mreal = pre ? MM1 : M2R;
    float* xcur = pre ? x : x2;
    bf16* xbcur = pre ? xb : xb2;

    k_cvt4<<<dim3(1024), dim3(256), 0, stream>>>(
        qkv_w + (size_t)l * 2304 * 768, onet_w + (size_t)l * 768 * 768,
        ff1_w + (size_t)l * 3072 * 768, ff2_w + (size_t)l * 768 * 3072,
        wq, wo, w1, w2, 2304 * 768 / 8, 768 * 768 / 8, 3072 * 768 / 8, 768 * 3072 / 8);

    k_gemm<3><<<dim3(18, Mp / 128), dim3(256), 0, stream>>>(xbcur, wq, qkv_b + (size_t)l * 2304,
                                                            nullptr, headsb, Mp, 3 * ED, ED);
    k_repack<<<dim3(TPu, BHN), dim3(64), 0, stream>>>(headsb, r_w_bias, r_r_bias, qw, qr, kkb, vT, T);
    k_scoreAC<<<dim3(TPu / 16, TPu / 16, BHN), dim3(64), 0, stream>>>(qw, kkb, S);
    k_scoreBD<<<dim3(TPu / 16, TPu / 16, BHN), dim3(64), 0, stream>>>(
        qr, rkb + (size_t)l * NH * TPM * 64, S, T);
    k_softmax<<<dim3(TPu, BHN), dim3(256), 0, stream>>>(S, prob, T, KPV);
    k_pv<<<dim3(TPu / 16, 4, BHN), dim3(64), 0, stream>>>(prob, vT, avb, T, KPV);
    k_gemm<0><<<dim3(6, Mp / 128), dim3(256), 0, stream>>>(avb, wo, onet_b + (size_t)l * 768,
                                                           gout, nullptr, Mp, ED, ED);
    k_ln<<<dim3(Mp), dim3(256), 0, stream>>>(xcur, gout, ln1_g + (size_t)l * 768, ln1_b + (size_t)l * 768,
                                             xcur, xbcur, Mreal);
    k_gemm<1><<<dim3(24, Mp / 128), dim3(256), 0, stream>>>(xbcur, w1, ff1_b + (size_t)l * 3072,
                                                            nullptr, hb, Mp, FFD, ED);
    k_gemm<0><<<dim3(6, Mp / 128), dim3(256), 0, stream>>>(hb, w2, ff2_b + (size_t)l * 768,
                                                           gout, nullptr, Mp, ED, FFD);
    k_ln<<<dim3(Mp), dim3(256), 0, stream>>>(xcur, gout, ln2_g + (size_t)l * 768, ln2_b + (size_t)l * 768,
                                             xcur, xbcur, Mreal);

    if (l == 1) {  // pool 196 -> {null} + 40 segments, LN -> short-stack input
      k_down<<<dim3(MM2), dim3(256), 0, stream>>>(x, null_tok, down_g, down_b, x2, xb2);
    }
  }

  // ---- final: token mean + classifier head (fp32) ----
  k_mean<<<dim3(NB), dim3(256), 0, stream>>>(x2, xm);
  k_head<<<dim3(8000), dim3(256), 0, stream>>>(xm, head_w, head_b, out);
}